// Round 1
// baseline (445.575 us; speedup 1.0000x reference)
//
#include <hip/hip_runtime.h>
#include <math.h>

#define N_NODES 100000
#define N_EDGES 1600000
#define F_IN 100
#define F_H 32

// ---------------------------------------------------------------- degree
__global__ void deg_kernel(const int* __restrict__ dst, float* __restrict__ deg,
                           int n_edges) {
    int e = blockIdx.x * blockDim.x + threadIdx.x;
    if (e < n_edges) atomicAdd(&deg[dst[e]], 1.0f);
}

__global__ void dinv_kernel(const float* __restrict__ deg, float* __restrict__ dinv,
                            int n) {
    int i = blockIdx.x * blockDim.x + threadIdx.x;
    if (i < n) dinv[i] = rsqrtf(deg[i] + 1.0f);  // +1 = self-loop
}

// ------------------------------------------------- h = x @ Wc; h2 = h*dinv
// block = 256 threads = 8 rows x 32 cols
__global__ void xw_kernel(const float* __restrict__ x, const float* __restrict__ W,
                          const float* __restrict__ dinv,
                          float* __restrict__ h2, float* __restrict__ acc,
                          int n_nodes) {
    __shared__ float Ws[F_IN * F_H];  // 12.8 KB
    for (int i = threadIdx.x; i < F_IN * F_H; i += blockDim.x) Ws[i] = W[i];
    __syncthreads();
    int row = blockIdx.x * 8 + (threadIdx.x >> 5);
    int col = threadIdx.x & 31;
    if (row >= n_nodes) return;
    const float* xr = x + (long)row * F_IN;
    float s = 0.f;
#pragma unroll 4
    for (int k = 0; k < F_IN; k++) s += xr[k] * Ws[k * F_H + col];
    float dv = dinv[row];
    float hs = s * dv;                 // h * dinv[n]
    h2[row * F_H + col] = hs;
    acc[row * F_H + col] = hs * dv;    // self-loop contribution h * dinv^2
}

// ---------------------------------------------------------- edge scatter
// one thread per (edge, col): acc[dst][c] += h2[src][c] * dinv[dst]
__global__ void scatter_kernel(const int* __restrict__ src, const int* __restrict__ dst,
                               const float* __restrict__ h2,
                               const float* __restrict__ dinv,
                               float* __restrict__ acc, int n_edges) {
    long gid = (long)blockIdx.x * blockDim.x + threadIdx.x;
    int e = (int)(gid >> 5);
    int c = (int)(gid & 31);
    if (e >= n_edges) return;
    int s = src[e];
    int d = dst[e];
    float val = h2[s * F_H + c] * dinv[d];
    atomicAdd(&acc[d * F_H + c], val);
}

// -------------------------------------- bias+relu, MLP 32->16->8->10, log_softmax
__global__ void mlp_kernel(const float* __restrict__ acc,
                           const float* __restrict__ bc,
                           const float* __restrict__ W1, const float* __restrict__ b1,
                           const float* __restrict__ W2, const float* __restrict__ b2,
                           const float* __restrict__ W3, const float* __restrict__ b3,
                           float* __restrict__ out, int n_nodes) {
    __shared__ float sbc[32];
    __shared__ float sW1[32 * 16], sb1[16];
    __shared__ float sW2[16 * 8],  sb2[8];
    __shared__ float sW3[8 * 10],  sb3[10];
    int t = threadIdx.x;
    if (t < 32) sbc[t] = bc[t];
    for (int i = t; i < 32 * 16; i += blockDim.x) sW1[i] = W1[i];
    if (t < 16) sb1[t] = b1[t];
    for (int i = t; i < 16 * 8; i += blockDim.x) sW2[i] = W2[i];
    if (t < 8) sb2[t] = b2[t];
    for (int i = t; i < 8 * 10; i += blockDim.x) sW3[i] = W3[i];
    if (t < 10) sb3[t] = b3[t];
    __syncthreads();

    int n = blockIdx.x * blockDim.x + t;
    if (n >= n_nodes) return;

    float a[32];
    const float4* ap = (const float4*)(acc + (long)n * 32);
#pragma unroll
    for (int q = 0; q < 8; q++) {
        float4 v = ap[q];
        a[q * 4 + 0] = fmaxf(v.x + sbc[q * 4 + 0], 0.f);
        a[q * 4 + 1] = fmaxf(v.y + sbc[q * 4 + 1], 0.f);
        a[q * 4 + 2] = fmaxf(v.z + sbc[q * 4 + 2], 0.f);
        a[q * 4 + 3] = fmaxf(v.w + sbc[q * 4 + 3], 0.f);
    }

    float t1[16];
#pragma unroll
    for (int j = 0; j < 16; j++) {
        float s = sb1[j];
        for (int k = 0; k < 32; k++) s += a[k] * sW1[k * 16 + j];
        t1[j] = fmaxf(s, 0.f);
    }
    float t2[8];
#pragma unroll
    for (int j = 0; j < 8; j++) {
        float s = sb2[j];
        for (int k = 0; k < 16; k++) s += t1[k] * sW2[k * 8 + j];
        t2[j] = fmaxf(s, 0.f);
    }
    float t3[10];
#pragma unroll
    for (int j = 0; j < 10; j++) {
        float s = sb3[j];
        for (int k = 0; k < 8; k++) s += t2[k] * sW3[k * 10 + j];
        t3[j] = s;
    }
    // log_softmax
    float m = t3[0];
#pragma unroll
    for (int j = 1; j < 10; j++) m = fmaxf(m, t3[j]);
    float se = 0.f;
#pragma unroll
    for (int j = 0; j < 10; j++) se += expf(t3[j] - m);
    float lse = logf(se) + m;
    float* op = out + (long)n * 10;
#pragma unroll
    for (int j = 0; j < 10; j++) op[j] = t3[j] - lse;
}

extern "C" void kernel_launch(void* const* d_in, const int* in_sizes, int n_in,
                              void* d_out, int out_size, void* d_ws, size_t ws_size,
                              hipStream_t stream) {
    const float* x  = (const float*)d_in[0];
    const int*   ei = (const int*)d_in[1];   // [2, E] int32
    // d_in[2] = edge_weight (unused by reference)
    const float* Wc = (const float*)d_in[3];
    const float* bc = (const float*)d_in[4];
    const float* W1 = (const float*)d_in[5];
    const float* b1 = (const float*)d_in[6];
    const float* W2 = (const float*)d_in[7];
    const float* b2 = (const float*)d_in[8];
    const float* W3 = (const float*)d_in[9];
    const float* b3 = (const float*)d_in[10];
    float* out = (float*)d_out;

    float* deg  = (float*)d_ws;                 // N_NODES
    float* dinv = deg + N_NODES;                // N_NODES
    float* h2   = dinv + N_NODES;               // N_NODES*32
    float* acc  = h2 + (long)N_NODES * F_H;     // N_NODES*32

    const int* srcp = ei;
    const int* dstp = ei + N_EDGES;

    hipMemsetAsync(deg, 0, N_NODES * sizeof(float), stream);
    deg_kernel<<<(N_EDGES + 255) / 256, 256, 0, stream>>>(dstp, deg, N_EDGES);
    dinv_kernel<<<(N_NODES + 255) / 256, 256, 0, stream>>>(deg, dinv, N_NODES);
    xw_kernel<<<(N_NODES + 7) / 8, 256, 0, stream>>>(x, Wc, dinv, h2, acc, N_NODES);
    long total = (long)N_EDGES * 32;
    scatter_kernel<<<(int)((total + 255) / 256), 256, 0, stream>>>(srcp, dstp, h2, dinv,
                                                                   acc, N_EDGES);
    mlp_kernel<<<(N_NODES + 255) / 256, 256, 0, stream>>>(acc, bc, W1, b1, W2, b2, W3,
                                                          b3, out, N_NODES);
}

// Round 2
// 427.337 us; speedup vs baseline: 1.0427x; 1.0427x over previous
//
#include <hip/hip_runtime.h>
#include <math.h>

#define N_NODES 100000
#define N_EDGES 1600000
#define F_IN 100
#define F_H 32
#define SCAN_B 256
#define SCAN_NB ((N_NODES + SCAN_B - 1) / SCAN_B)  // 391 blocks

// ------------------------------------------------ histogram of dst (= degree w/o self-loop)
__global__ void hist_kernel(const int* __restrict__ dst, int* __restrict__ counts) {
    int e = blockIdx.x * blockDim.x + threadIdx.x;
    if (e < N_EDGES) atomicAdd(&counts[dst[e]], 1);
}

// ------------------------------------------------ scan stage 1: per-block exclusive scan
__global__ void scan1_kernel(const int* __restrict__ counts, int* __restrict__ row_start,
                             int* __restrict__ bsum, float* __restrict__ dinv) {
    __shared__ int s[SCAN_B];
    int t = threadIdx.x;
    int i = blockIdx.x * SCAN_B + t;
    int v = (i < N_NODES) ? counts[i] : 0;
    if (i < N_NODES) dinv[i] = rsqrtf((float)v + 1.0f);  // +1 self-loop
    s[t] = v;
    __syncthreads();
    for (int off = 1; off < SCAN_B; off <<= 1) {
        int x = (t >= off) ? s[t - off] : 0;
        __syncthreads();
        s[t] += x;
        __syncthreads();
    }
    if (i < N_NODES) row_start[i] = s[t] - v;  // exclusive
    if (t == SCAN_B - 1) bsum[blockIdx.x] = s[t];
}

// ------------------------------------------------ scan stage 2: scan the 391 block sums
__global__ void scan2_kernel(int* __restrict__ bsum, int nb) {
    __shared__ int s[512];
    int t = threadIdx.x;
    int v = (t < nb) ? bsum[t] : 0;
    s[t] = v;
    __syncthreads();
    for (int off = 1; off < 512; off <<= 1) {
        int x = (t >= off) ? s[t - off] : 0;
        __syncthreads();
        s[t] += x;
        __syncthreads();
    }
    if (t < nb) bsum[t] = s[t] - v;  // exclusive block offsets
}

// ------------------------------------------------ scan stage 3: add offsets, init cursor
__global__ void scan3_kernel(int* __restrict__ row_start, const int* __restrict__ bsum,
                             int* __restrict__ cursor) {
    int i = blockIdx.x * SCAN_B + threadIdx.x;
    if (i < N_NODES) {
        int v = row_start[i] + bsum[i >> 8];  // SCAN_B == 256
        row_start[i] = v;
        cursor[i] = v;
    }
    if (i == 0) row_start[N_NODES] = N_EDGES;
}

// ------------------------------------------------ fill CSR src lists
__global__ void fill_kernel(const int* __restrict__ src, const int* __restrict__ dst,
                            int* __restrict__ cursor, int* __restrict__ csr_src) {
    int e = blockIdx.x * blockDim.x + threadIdx.x;
    if (e < N_EDGES) {
        int d = dst[e];
        int pos = atomicAdd(&cursor[d], 1);
        csr_src[pos] = src[e];
    }
}

// ------------------------------------------------ h2 = (x @ Wc) * dinv[row]
// block = 256 threads = 8 rows x 32 cols
__global__ void xw_kernel(const float* __restrict__ x, const float* __restrict__ W,
                          const float* __restrict__ dinv, float* __restrict__ h2,
                          int n_nodes) {
    __shared__ float Ws[F_IN * F_H];  // 12.8 KB
    for (int i = threadIdx.x; i < F_IN * F_H; i += blockDim.x) Ws[i] = W[i];
    __syncthreads();
    int row = blockIdx.x * 8 + (threadIdx.x >> 5);
    int col = threadIdx.x & 31;
    if (row >= n_nodes) return;
    const float* xr = x + (long)row * F_IN;
    float s = 0.f;
#pragma unroll 4
    for (int k = 0; k < F_IN; k++) s += xr[k] * Ws[k * F_H + col];
    h2[row * F_H + col] = s * dinv[row];
}

// ------------------------------------------------ gather: acc[n] = (sum h2[src] + h2[n]) * dinv[n]
__global__ void gather_kernel(const int* __restrict__ row_start,
                              const int* __restrict__ csr_src,
                              const float* __restrict__ h2,
                              const float* __restrict__ dinv,
                              float* __restrict__ acc) {
    int gid = blockIdx.x * blockDim.x + threadIdx.x;
    int n = gid >> 5;
    int col = gid & 31;
    if (n >= N_NODES) return;
    int beg = row_start[n];
    int end = row_start[n + 1];
    float sum = h2[n * F_H + col];  // self-loop term
    int e = beg;
    for (; e + 4 <= end; e += 4) {  // 4 independent gathers in flight
        int s0 = csr_src[e], s1 = csr_src[e + 1], s2 = csr_src[e + 2], s3 = csr_src[e + 3];
        float v0 = h2[s0 * F_H + col];
        float v1 = h2[s1 * F_H + col];
        float v2 = h2[s2 * F_H + col];
        float v3 = h2[s3 * F_H + col];
        sum += v0 + v1 + v2 + v3;
    }
    for (; e < end; e++) sum += h2[csr_src[e] * F_H + col];
    acc[n * F_H + col] = sum * dinv[n];
}

// -------------------------------------- bias+relu, MLP 32->16->8->10, log_softmax
__global__ void mlp_kernel(const float* __restrict__ acc, const float* __restrict__ bc,
                           const float* __restrict__ W1, const float* __restrict__ b1,
                           const float* __restrict__ W2, const float* __restrict__ b2,
                           const float* __restrict__ W3, const float* __restrict__ b3,
                           float* __restrict__ out, int n_nodes) {
    __shared__ float sbc[32];
    __shared__ float sW1[32 * 16], sb1[16];
    __shared__ float sW2[16 * 8], sb2[8];
    __shared__ float sW3[8 * 10], sb3[10];
    int t = threadIdx.x;
    if (t < 32) sbc[t] = bc[t];
    for (int i = t; i < 32 * 16; i += blockDim.x) sW1[i] = W1[i];
    if (t < 16) sb1[t] = b1[t];
    for (int i = t; i < 16 * 8; i += blockDim.x) sW2[i] = W2[i];
    if (t < 8) sb2[t] = b2[t];
    for (int i = t; i < 8 * 10; i += blockDim.x) sW3[i] = W3[i];
    if (t < 10) sb3[t] = b3[t];
    __syncthreads();

    int n = blockIdx.x * blockDim.x + t;
    if (n >= n_nodes) return;

    float a[32];
    const float4* ap = (const float4*)(acc + (long)n * 32);
#pragma unroll
    for (int q = 0; q < 8; q++) {
        float4 v = ap[q];
        a[q * 4 + 0] = fmaxf(v.x + sbc[q * 4 + 0], 0.f);
        a[q * 4 + 1] = fmaxf(v.y + sbc[q * 4 + 1], 0.f);
        a[q * 4 + 2] = fmaxf(v.z + sbc[q * 4 + 2], 0.f);
        a[q * 4 + 3] = fmaxf(v.w + sbc[q * 4 + 3], 0.f);
    }

    float t1[16];
#pragma unroll
    for (int j = 0; j < 16; j++) {
        float s = sb1[j];
        for (int k = 0; k < 32; k++) s += a[k] * sW1[k * 16 + j];
        t1[j] = fmaxf(s, 0.f);
    }
    float t2[8];
#pragma unroll
    for (int j = 0; j < 8; j++) {
        float s = sb2[j];
        for (int k = 0; k < 16; k++) s += t1[k] * sW2[k * 8 + j];
        t2[j] = fmaxf(s, 0.f);
    }
    float t3[10];
#pragma unroll
    for (int j = 0; j < 10; j++) {
        float s = sb3[j];
        for (int k = 0; k < 8; k++) s += t2[k] * sW3[k * 10 + j];
        t3[j] = s;
    }
    float m = t3[0];
#pragma unroll
    for (int j = 1; j < 10; j++) m = fmaxf(m, t3[j]);
    float se = 0.f;
#pragma unroll
    for (int j = 0; j < 10; j++) se += expf(t3[j] - m);
    float lse = logf(se) + m;
    float* op = out + (long)n * 10;
#pragma unroll
    for (int j = 0; j < 10; j++) op[j] = t3[j] - lse;
}

extern "C" void kernel_launch(void* const* d_in, const int* in_sizes, int n_in,
                              void* d_out, int out_size, void* d_ws, size_t ws_size,
                              hipStream_t stream) {
    const float* x  = (const float*)d_in[0];
    const int*   ei = (const int*)d_in[1];  // [2, E] int32
    const float* Wc = (const float*)d_in[3];
    const float* bc = (const float*)d_in[4];
    const float* W1 = (const float*)d_in[5];
    const float* b1 = (const float*)d_in[6];
    const float* W2 = (const float*)d_in[7];
    const float* b2 = (const float*)d_in[8];
    const float* W3 = (const float*)d_in[9];
    const float* b3 = (const float*)d_in[10];
    float* out = (float*)d_out;

    // workspace layout (all 4-byte elems): ~33.6 MB
    int*   counts    = (int*)d_ws;                    // N
    int*   row_start = counts + N_NODES;              // N+1
    int*   bsum      = row_start + N_NODES + 1;       // 512
    int*   cursor    = bsum + 512;                    // N
    int*   csr_src   = cursor + N_NODES;              // E
    float* dinv      = (float*)(csr_src + N_EDGES);   // N
    float* h2        = dinv + N_NODES;                // N*32
    float* acc       = h2 + (long)N_NODES * F_H;      // N*32

    const int* srcp = ei;
    const int* dstp = ei + N_EDGES;

    hipMemsetAsync(counts, 0, N_NODES * sizeof(int), stream);
    hist_kernel<<<(N_EDGES + 255) / 256, 256, 0, stream>>>(dstp, counts);
    scan1_kernel<<<SCAN_NB, SCAN_B, 0, stream>>>(counts, row_start, bsum, dinv);
    scan2_kernel<<<1, 512, 0, stream>>>(bsum, SCAN_NB);
    scan3_kernel<<<SCAN_NB, SCAN_B, 0, stream>>>(row_start, bsum, cursor);
    fill_kernel<<<(N_EDGES + 255) / 256, 256, 0, stream>>>(srcp, dstp, cursor, csr_src);
    xw_kernel<<<(N_NODES + 7) / 8, 256, 0, stream>>>(x, Wc, dinv, h2, N_NODES);
    gather_kernel<<<(N_NODES * 32 + 255) / 256, 256, 0, stream>>>(row_start, csr_src, h2,
                                                                  dinv, acc);
    mlp_kernel<<<(N_NODES + 255) / 256, 256, 0, stream>>>(acc, bc, W1, b1, W2, b2, W3,
                                                          b3, out, N_NODES);
}